// Round 16
// baseline (189.377 us; speedup 1.0000x reference)
//
#include <hip/hip_runtime.h>
#include <hip/hip_fp16.h>
#include <math.h>

typedef unsigned short u16;
typedef unsigned int u32;
typedef __attribute__((ext_vector_type(8))) _Float16 half8v;
typedef __attribute__((ext_vector_type(4))) float float4v;

#define BKT_SH 7                    // 128 nodes per bucket
#define BKT_CAP 4096                // >> mean occupancy 2176 (uniform dst)
#define BKT_MAX 512                 // max buckets (n <= 65536; src fits 16 bits)
#define TILE 8192                   // edges per bucket_append block

__device__ __forceinline__ u16 f2h(float f) {
    __half h = __float2half(f);
    return __half_as_ushort(h);
}

// ---------------- weight prep: W [128][128] f32 -> WT [col][k] fp16 ----------
__global__ void prep_w(const float* __restrict__ W1, const float* __restrict__ W2,
                       u16* __restrict__ WT1, u16* __restrict__ WT2) {
    int t = blockIdx.x * 256 + threadIdx.x;   // 32768 total
    int which = t >> 14, idx = t & 16383;
    int k = idx >> 7, c = idx & 127;
    const float* W = which ? W2 : W1;
    u16* WT = which ? WT2 : WT1;
    WT[c * 128 + k] = f2h(W[k * 128 + c]);
}

// ---------------- MFMA GEMM (fp16) + fused alpha_src/alpha_dst ---------------
template <int IN16, int H>
__global__ __launch_bounds__(256) void gemm_mfma(const void* __restrict__ Xv,
                                                 const u16* __restrict__ WT,
                                                 const float* __restrict__ a_src,
                                                 const float* __restrict__ a_dst,
                                                 u16* __restrict__ Hb,
                                                 float* __restrict__ AS,
                                                 float* __restrict__ AD, int n) {
    __shared__ __align__(16) u16 xs[64][136];
    __shared__ __align__(16) u16 ws[128][136];
    const int t = threadIdx.x;
    const int n0 = blockIdx.x * 64;

    {
        const uint4* src = (const uint4*)WT;
        #pragma unroll
        for (int i = 0; i < 8; ++i) {
            int idx = t + i * 256;
            int row = idx >> 4, oct = idx & 15;
            uint4 v = src[idx];
            *(uint4*)&ws[row][oct * 8] = v;
        }
    }
    if (IN16) {
        const u16* X = (const u16*)Xv;
        #pragma unroll
        for (int i = 0; i < 4; ++i) {
            int idx = t + i * 256;
            int row = idx >> 4, oct = idx & 15;
            uint4 v = make_uint4(0, 0, 0, 0);
            if (n0 + row < n) v = *(const uint4*)&X[(size_t)(n0 + row) * 128 + oct * 8];
            *(uint4*)&xs[row][oct * 8] = v;
        }
    } else {
        const float* X = (const float*)Xv;
        #pragma unroll
        for (int i = 0; i < 8; ++i) {
            int idx = t + i * 256;
            int row = idx >> 5, quad = idx & 31;
            float4 v = make_float4(0.f, 0.f, 0.f, 0.f);
            if (n0 + row < n) v = *(const float4*)&X[(size_t)(n0 + row) * 128 + quad * 4];
            u32 lo = (u32)f2h(v.x) | ((u32)f2h(v.y) << 16);
            u32 hi = (u32)f2h(v.z) | ((u32)f2h(v.w) << 16);
            *(uint2*)&xs[row][quad * 4] = make_uint2(lo, hi);
        }
    }
    __syncthreads();

    const int wave = t >> 6, lane = t & 63;
    const int r0 = wave * 16;
    const int kcol = lane & 15;
    const int arow = r0 + kcol;
    const int kb = (lane >> 4) * 8;

    float4v acc[8];
    #pragma unroll
    for (int j = 0; j < 8; ++j) acc[j] = (float4v){0.f, 0.f, 0.f, 0.f};

    #pragma unroll
    for (int kk = 0; kk < 4; ++kk) {
        const int k0 = kk * 32 + kb;
        half8v a = *(const half8v*)&xs[arow][k0];
        #pragma unroll
        for (int j = 0; j < 8; ++j) {
            half8v b = *(const half8v*)&ws[j * 16 + kcol][k0];
            acc[j] = __builtin_amdgcn_mfma_f32_16x16x32_f16(a, b, acc[j], 0, 0, 0);
        }
    }

    const int rbase = n0 + r0 + (lane >> 4) * 4;
    #pragma unroll
    for (int j = 0; j < 8; ++j) {
        #pragma unroll
        for (int r = 0; r < 4; ++r) {
            int row = rbase + r;
            if (row < n) Hb[(size_t)row * 128 + j * 16 + kcol] = f2h(acc[j][r]);
        }
    }

    float av[8], bv[8];
    #pragma unroll
    for (int j = 0; j < 8; ++j) {
        av[j] = a_src[j * 16 + kcol];
        bv[j] = a_dst[j * 16 + kcol];
    }

    if (H == 4) {
        float ps[4][4], pd[4][4];
        #pragma unroll
        for (int r = 0; r < 4; ++r)
            #pragma unroll
            for (int h = 0; h < 4; ++h) {
                ps[r][h] = acc[2*h][r] * av[2*h] + acc[2*h+1][r] * av[2*h+1];
                pd[r][h] = acc[2*h][r] * bv[2*h] + acc[2*h+1][r] * bv[2*h+1];
            }
        #pragma unroll
        for (int o = 8; o >= 1; o >>= 1)
            #pragma unroll
            for (int r = 0; r < 4; ++r)
                #pragma unroll
                for (int h = 0; h < 4; ++h) {
                    ps[r][h] += __shfl_xor(ps[r][h], o);
                    pd[r][h] += __shfl_xor(pd[r][h], o);
                }
        float wvs = 0.f, wvd = 0.f;
        #pragma unroll
        for (int r = 0; r < 4; ++r)
            #pragma unroll
            for (int h = 0; h < 4; ++h)
                if (kcol == r * 4 + h) { wvs = ps[r][h]; wvd = pd[r][h]; }
        int node = rbase + (kcol >> 2);
        if (node < n) {
            AS[node * 4 + (kcol & 3)] = wvs;
            AD[node * 4 + (kcol & 3)] = wvd;
        }
    } else {
        float ps[4], pd[4];
        #pragma unroll
        for (int r = 0; r < 4; ++r) {
            float s_ = 0.f, d_ = 0.f;
            #pragma unroll
            for (int j = 0; j < 8; ++j) {
                s_ += acc[j][r] * av[j];
                d_ += acc[j][r] * bv[j];
            }
            ps[r] = s_; pd[r] = d_;
        }
        #pragma unroll
        for (int o = 8; o >= 1; o >>= 1)
            #pragma unroll
            for (int r = 0; r < 4; ++r) {
                ps[r] += __shfl_xor(ps[r], o);
                pd[r] += __shfl_xor(pd[r], o);
            }
        float val = 0.f;
        #pragma unroll
        for (int r = 0; r < 4; ++r)
            if ((kcol & 3) == r) val = (kcol < 4) ? ps[r] : pd[r];
        int node = rbase + (kcol & 3);
        if (kcol < 8 && node < n) {
            if (kcol < 4) AS[node] = val;
            else          AD[node] = val;
        }
    }
}

// ---------------- bucketed CSR build ----------------------------------------
__global__ __launch_bounds__(256) void bucket_append(
    const int* __restrict__ ei, int* __restrict__ bcnt,
    u32* __restrict__ bkt, int E, int etot, int nbkt) {
    __shared__ u32 ent[TILE];
    __shared__ int hist[BKT_MAX], lstart[BKT_MAX], gbase[BKT_MAX], cur[BKT_MAX];
    __shared__ int sc[BKT_MAX];
    const int t = threadIdx.x;
    const int e0 = blockIdx.x * TILE;
    const int cnt = min(TILE, etot - e0);

    for (int i = t; i < BKT_MAX; i += 256) { hist[i] = 0; }
    __syncthreads();

    for (int i = t; i < cnt; i += 256) {
        int e = e0 + i;
        int d = (e < E) ? ei[E + e] : e - E;
        atomicAdd(&hist[d >> BKT_SH], 1);
    }
    __syncthreads();

    sc[t] = hist[t];
    sc[t + 256] = hist[t + 256];
    __syncthreads();
    for (int off = 1; off < BKT_MAX; off <<= 1) {
        int i0 = t, i1 = t + 256;
        int v0 = (i0 >= off) ? sc[i0 - off] : 0;
        int v1 = (i1 >= off) ? sc[i1 - off] : 0;
        __syncthreads();
        sc[i0] += v0;
        sc[i1] += v1;
        __syncthreads();
    }
    for (int i = t; i < BKT_MAX; i += 256) {
        int ls = sc[i] - hist[i];
        lstart[i] = ls;
        cur[i] = ls;
        gbase[i] = (i < nbkt && hist[i] > 0) ? atomicAdd(&bcnt[i * 16], hist[i]) : 0;
    }
    __syncthreads();

    for (int i = t; i < cnt; i += 256) {
        int e = e0 + i;
        int s, d;
        if (e < E) { s = ei[e]; d = ei[E + e]; } else { s = d = e - E; }
        int p = atomicAdd(&cur[d >> BKT_SH], 1);
        ent[p] = ((u32)d << 16) | (u32)s;
    }
    __syncthreads();

    for (int i = t; i < cnt; i += 256) {
        u32 en = ent[i];
        int b = en >> (16 + BKT_SH);
        int pos = gbase[b] + (i - lstart[b]);
        if (pos < BKT_CAP) bkt[(size_t)b * BKT_CAP + pos] = en;
    }
}

__global__ __launch_bounds__(256) void bucket_csr(
    const u32* __restrict__ bkt, const int* __restrict__ bcnt,
    int* __restrict__ offsets, int* __restrict__ csr_src,
    int n, int nbkt, int etot) {
    __shared__ u32 ent[BKT_CAP];
    __shared__ int hist[128], pr[128], cur[128];
    __shared__ int sc[BKT_MAX];
    const int b = blockIdx.x;
    const int t = threadIdx.x;

    sc[t]       = (t < nbkt)       ? min(bcnt[t * 16], BKT_CAP) : 0;
    sc[t + 256] = (t + 256 < nbkt) ? min(bcnt[(t + 256) * 16], BKT_CAP) : 0;
    __syncthreads();
    for (int off = 1; off < BKT_MAX; off <<= 1) {
        int i0 = t, i1 = t + 256;
        int v0 = (i0 >= off) ? sc[i0 - off] : 0;
        int v1 = (i1 >= off) ? sc[i1 - off] : 0;
        __syncthreads();
        sc[i0] += v0;
        sc[i1] += v1;
        __syncthreads();
    }
    const int cnt = min(bcnt[b * 16], BKT_CAP);
    const int base = sc[b] - cnt;
    if (b == 0 && t == 0) offsets[n] = etot;

    for (int i = t; i < cnt; i += 256) ent[i] = bkt[(size_t)b * BKT_CAP + i];
    if (t < 128) hist[t] = 0;
    __syncthreads();
    for (int i = t; i < cnt; i += 256) atomicAdd(&hist[(ent[i] >> 16) & 127], 1);
    __syncthreads();
    if (t < 128) pr[t] = hist[t];
    __syncthreads();
    #pragma unroll
    for (int off = 1; off < 128; off <<= 1) {
        int u = (t >= off && t < 128) ? pr[t - off] : 0;
        __syncthreads();
        if (t < 128) pr[t] += u;
        __syncthreads();
    }
    if (t < 128) {
        int excl = pr[t] - hist[t];
        int d = b * 128 + t;
        if (d < n) offsets[d] = base + excl;
        cur[t] = excl;
    }
    __syncthreads();
    for (int i = t; i < cnt; i += 256) {
        u32 en = ent[i];
        int dl = (en >> 16) & 127;
        int pos = base + atomicAdd(&cur[dl], 1);
        csr_src[pos] = (int)(en & 0xFFFFu);
    }
}

// ---------------- single-pass fused softmax + aggregation (2 waves/node) -----
// Channel-split: wave w of node d owns channels 64w..64w+63. Lane = q*8 + c:
// edge subslot q (0..7, 8 edges per wave-load!), channel octet c (8 fp16 =
// 16B uint4). Alpha slots/denominator computed redundantly in both waves
// (VALU is not the limiter -- r13 vs r15 A/B). Combine acc over q via
// shfl_xor(8,16,32); lanes 0-7 write. Doubles wave count (latency hiding).
// ghead = channel_base>>5. MODE 0: OUT fp16 elu(agg+bias); MODE 1: f32.
template <int H, int MODE>
__global__ __launch_bounds__(256) void node_fused(
    const int* __restrict__ offsets, const int* __restrict__ csr_src,
    const float* __restrict__ AS, const float* __restrict__ AD,
    const u16* __restrict__ Hb, const float* __restrict__ bias,
    void* __restrict__ OUT, int n) {
    const int wid = threadIdx.x >> 6, lane = threadIdx.x & 63;
    const int d = blockIdx.x * 2 + (wid >> 1);   // 2 nodes per block
    const int w = wid & 1;                       // channel half
    if (d >= n) return;
    const int off = offsets[d];
    const int deg = offsets[d + 1] - off;

    constexpr int SCH = (H == 4) ? 32 : 64;
    const int slot = (H == 4) ? (lane & 15) : lane;   // alpha slot
    const int g    = (H == 4) ? (lane >> 4) : 0;      // head this alpha covers
    const float adv = AD[d * H + g];

    const int q  = lane >> 3;                         // edge subslot 0..7
    const int cb = w * 64 + (lane & 7) * 8;           // my 8 channels: cb..cb+7
    const int ghead = (H == 4) ? (cb >> 5) : 0;       // head of my channels

    float acc[8];
    #pragma unroll
    for (int j = 0; j < 8; ++j) acc[j] = 0.f;
    float smp = 0.f;

    // prefetch chunk 0 alpha inputs (A = slots 0..15, B = slots 16..31 for H=4)
    int sA = 0, sB = 0;
    float xA = 0.f, xB = 0.f, vA = 0.f, vB = 0.f;
    {
        int kA = slot; bool a = kA < deg;
        sA = a ? csr_src[off + kA] : 0;
        xA = a ? AS[sA * H + g] : 0.f;
        vA = a ? 1.f : 0.f;
        if (H == 4) {
            int kB = 16 + slot; bool b_ = kB < deg;
            sB = b_ ? csr_src[off + kB] : 0;
            xB = b_ ? AS[sB * H + g] : 0.f;
            vB = b_ ? 1.f : 0.f;
        }
    }

    for (int k0 = 0; k0 < deg; k0 += SCH) {
        float eA = xA + adv; eA = eA > 0.f ? eA : 0.2f * eA;
        float aA = vA * __expf(eA);
        float aB = 0.f;
        if (H == 4) {
            float eB = xB + adv; eB = eB > 0.f ? eB : 0.2f * eB;
            aB = vB * __expf(eB);
        }
        smp += aA + aB;
        const int scA = sA, scB = sB;

        // prefetch next chunk
        {
            int kA = k0 + SCH + slot; bool a = kA < deg;
            sA = a ? csr_src[off + kA] : 0;
            xA = a ? AS[sA * H + g] : 0.f;
            vA = a ? 1.f : 0.f;
            if (H == 4) {
                int kB = k0 + SCH + 16 + slot; bool b_ = kB < deg;
                sB = b_ ? csr_src[off + kB] : 0;
                xB = b_ ? AS[sB * H + g] : 0.f;
                vB = b_ ? 1.f : 0.f;
            }
        }

        const int rem = min(SCH, deg - k0);
        const int ngr = (rem + 7) >> 3;               // 8-edge groups
        #pragma unroll
        for (int p = 0; p < SCH / 8; ++p) {
            if (p >= ngr) break;                      // wave-uniform
            const int eslot = p * 8 + q;
            float al; int sj;
            if (H == 4) {
                if (p < 2) {
                    al = __shfl(aA, ghead * 16 + eslot);
                    sj = __shfl(scA, ghead * 16 + eslot);
                } else {
                    al = __shfl(aB, ghead * 16 + eslot - 16);
                    sj = __shfl(scB, ghead * 16 + eslot - 16);
                }
            } else {
                al = __shfl(aA, eslot);
                sj = __shfl(scA, eslot);
            }
            uint4 u = *(const uint4*)&Hb[(size_t)sj * 128 + cb];
            __half2 p0 = *(__half2*)&u.x;
            __half2 p1 = *(__half2*)&u.y;
            __half2 p2 = *(__half2*)&u.z;
            __half2 p3 = *(__half2*)&u.w;
            acc[0] += __low2float(p0) * al; acc[1] += __high2float(p0) * al;
            acc[2] += __low2float(p1) * al; acc[3] += __high2float(p1) * al;
            acc[4] += __low2float(p2) * al; acc[5] += __high2float(p2) * al;
            acc[6] += __low2float(p3) * al; acc[7] += __high2float(p3) * al;
        }
    }

    // denominator: butterfly (per head group for H=4), route to my head
    #pragma unroll
    for (int o = (H == 4 ? 8 : 32); o >= 1; o >>= 1)
        smp += __shfl_xor(smp, o);
    const float den = (H == 4) ? __shfl(smp, ghead * 16) : smp;
    const float dinv = 1.f / den;

    // combine edge-subslot partials (q spans lane bits 3..5)
    #pragma unroll
    for (int j = 0; j < 8; ++j) {
        acc[j] += __shfl_xor(acc[j], 8);
        acc[j] += __shfl_xor(acc[j], 16);
        acc[j] += __shfl_xor(acc[j], 32);
    }

    if (lane < 8) {
        const float4 bv0 = *(const float4*)&bias[cb];
        const float4 bv1 = *(const float4*)&bias[cb + 4];
        float o_[8];
        o_[0] = acc[0] * dinv + bv0.x; o_[1] = acc[1] * dinv + bv0.y;
        o_[2] = acc[2] * dinv + bv0.z; o_[3] = acc[3] * dinv + bv0.w;
        o_[4] = acc[4] * dinv + bv1.x; o_[5] = acc[5] * dinv + bv1.y;
        o_[6] = acc[6] * dinv + bv1.z; o_[7] = acc[7] * dinv + bv1.w;
        if (MODE == 0) {
            #pragma unroll
            for (int j = 0; j < 8; ++j) o_[j] = o_[j] > 0.f ? o_[j] : expm1f(o_[j]);
            uint4 pk;
            pk.x = (u32)f2h(o_[0]) | ((u32)f2h(o_[1]) << 16);
            pk.y = (u32)f2h(o_[2]) | ((u32)f2h(o_[3]) << 16);
            pk.z = (u32)f2h(o_[4]) | ((u32)f2h(o_[5]) << 16);
            pk.w = (u32)f2h(o_[6]) | ((u32)f2h(o_[7]) << 16);
            *(uint4*)&((u16*)OUT)[(size_t)d * 128 + cb] = pk;
        } else {
            float* O = (float*)OUT;
            *(float4*)&O[(size_t)d * 128 + cb]     = make_float4(o_[0], o_[1], o_[2], o_[3]);
            *(float4*)&O[(size_t)d * 128 + cb + 4] = make_float4(o_[4], o_[5], o_[6], o_[7]);
        }
    }
}

// ---------------- launch -----------------------------------------------------
extern "C" void kernel_launch(void* const* d_in, const int* in_sizes, int n_in,
                              void* d_out, int out_size, void* d_ws, size_t ws_size,
                              hipStream_t stream) {
    const float* x   = (const float*)d_in[0];
    const int*   ei  = (const int*)d_in[1];
    const float* W1  = (const float*)d_in[2];
    const float* as1 = (const float*)d_in[3];
    const float* ad1 = (const float*)d_in[4];
    const float* b1  = (const float*)d_in[5];
    const float* W2  = (const float*)d_in[6];
    const float* as2 = (const float*)d_in[7];
    const float* ad2 = (const float*)d_in[8];
    const float* b2  = (const float*)d_in[9];
    float* out = (float*)d_out;

    const int n = in_sizes[0] / 128;
    const int E = in_sizes[1] / 2;
    const int etot = E + n;
    const int nbkt = (n + 127) >> BKT_SH;

    char* p = (char*)d_ws;
    u16* Hb1 = (u16*)p; p += (size_t)n * 128 * 2;
    u16* Xb2 = (u16*)p; p += (size_t)n * 128 * 2;
    u16* Hb2 = (u16*)p; p += (size_t)n * 128 * 2;
    float* AS = (float*)p; p += (size_t)n * 4 * 4;
    float* AD = (float*)p; p += (size_t)n * 4 * 4;
    u16* WT1 = (u16*)p; p += 32768;
    u16* WT2 = (u16*)p; p += 32768;
    u32* bkt     = (u32*)p; p += (size_t)BKT_MAX * BKT_CAP * 4;   // 8 MB
    int* bcnt    = (int*)p; p += (size_t)BKT_MAX * 16 * 4;        // line-padded
    int* csr_src = (int*)p; p += (size_t)etot * 4;
    int* offsets = (int*)p; p += (size_t)(n + 1) * 4;

    const int ggrid = (n + 63) / 64;
    const int ngrid = (n + 1) / 2;                  // 2 nodes per block now
    const int agrid = (etot + TILE - 1) / TILE;

    prep_w<<<128, 256, 0, stream>>>(W1, W2, WT1, WT2);
    (void)hipMemsetAsync(bcnt, 0, (size_t)BKT_MAX * 16 * 4, stream);
    bucket_append<<<agrid, 256, 0, stream>>>(ei, bcnt, bkt, E, etot, nbkt);
    bucket_csr<<<nbkt, 256, 0, stream>>>(bkt, bcnt, offsets, csr_src, n, nbkt, etot);

    // ---- layer 1 (H=4, concat, ELU fused) ----
    gemm_mfma<0, 4><<<ggrid, 256, 0, stream>>>(x, WT1, as1, ad1, Hb1, AS, AD, n);
    node_fused<4, 0><<<ngrid, 256, 0, stream>>>(offsets, csr_src, AS, AD, Hb1, b1, Xb2, n);

    // ---- layer 2 (H=1, mean over 1 head = identity) ----
    gemm_mfma<1, 1><<<ggrid, 256, 0, stream>>>(Xb2, WT2, as2, ad2, Hb2, AS, AD, n);
    node_fused<1, 1><<<ngrid, 256, 0, stream>>>(offsets, csr_src, AS, AD, Hb2, b2, out, n);
}

// Round 17
// 146.449 us; speedup vs baseline: 1.2931x; 1.2931x over previous
//
#include <hip/hip_runtime.h>
#include <hip/hip_fp16.h>
#include <math.h>

typedef unsigned short u16;
typedef unsigned int u32;
typedef __attribute__((ext_vector_type(8))) _Float16 half8v;
typedef __attribute__((ext_vector_type(4))) float float4v;

#define BKT_SH 7                    // 128 nodes per bucket
#define BKT_CAP 4096                // >> mean occupancy 2176 (uniform dst)
#define BKT_MAX 512                 // max buckets (n <= 65536; src fits 16 bits)
#define TILE 4096                   // edges per bucket_append block (r17: was 8192)

__device__ __forceinline__ u16 f2h(float f) {
    __half h = __float2half(f);
    return __half_as_ushort(h);
}

// ---------------- weight prep: W f32 -> WT [col][k] fp16 ; zeros bcnt --------
__global__ void prep_w(const float* __restrict__ W1, const float* __restrict__ W2,
                       u16* __restrict__ WT1, u16* __restrict__ WT2,
                       int* __restrict__ bcnt) {
    int t = blockIdx.x * 256 + threadIdx.x;   // 32768 total
    if (t < BKT_MAX * 16) bcnt[t] = 0;        // fused memset (8192 ints)
    int which = t >> 14, idx = t & 16383;
    int k = idx >> 7, c = idx & 127;
    const float* W = which ? W2 : W1;
    u16* WT = which ? WT2 : WT1;
    WT[c * 128 + k] = f2h(W[k * 128 + c]);
}

// ---------------- MFMA GEMM (fp16) + fused alpha_src/alpha_dst ---------------
template <int IN16, int H>
__global__ __launch_bounds__(256) void gemm_mfma(const void* __restrict__ Xv,
                                                 const u16* __restrict__ WT,
                                                 const float* __restrict__ a_src,
                                                 const float* __restrict__ a_dst,
                                                 u16* __restrict__ Hb,
                                                 float* __restrict__ AS,
                                                 float* __restrict__ AD, int n) {
    __shared__ __align__(16) u16 xs[64][136];
    __shared__ __align__(16) u16 ws[128][136];
    const int t = threadIdx.x;
    const int n0 = blockIdx.x * 64;

    {
        const uint4* src = (const uint4*)WT;
        #pragma unroll
        for (int i = 0; i < 8; ++i) {
            int idx = t + i * 256;
            int row = idx >> 4, oct = idx & 15;
            uint4 v = src[idx];
            *(uint4*)&ws[row][oct * 8] = v;
        }
    }
    if (IN16) {
        const u16* X = (const u16*)Xv;
        #pragma unroll
        for (int i = 0; i < 4; ++i) {
            int idx = t + i * 256;
            int row = idx >> 4, oct = idx & 15;
            uint4 v = make_uint4(0, 0, 0, 0);
            if (n0 + row < n) v = *(const uint4*)&X[(size_t)(n0 + row) * 128 + oct * 8];
            *(uint4*)&xs[row][oct * 8] = v;
        }
    } else {
        const float* X = (const float*)Xv;
        #pragma unroll
        for (int i = 0; i < 8; ++i) {
            int idx = t + i * 256;
            int row = idx >> 5, quad = idx & 31;
            float4 v = make_float4(0.f, 0.f, 0.f, 0.f);
            if (n0 + row < n) v = *(const float4*)&X[(size_t)(n0 + row) * 128 + quad * 4];
            u32 lo = (u32)f2h(v.x) | ((u32)f2h(v.y) << 16);
            u32 hi = (u32)f2h(v.z) | ((u32)f2h(v.w) << 16);
            *(uint2*)&xs[row][quad * 4] = make_uint2(lo, hi);
        }
    }
    __syncthreads();

    const int wave = t >> 6, lane = t & 63;
    const int r0 = wave * 16;
    const int kcol = lane & 15;
    const int arow = r0 + kcol;
    const int kb = (lane >> 4) * 8;

    float4v acc[8];
    #pragma unroll
    for (int j = 0; j < 8; ++j) acc[j] = (float4v){0.f, 0.f, 0.f, 0.f};

    #pragma unroll
    for (int kk = 0; kk < 4; ++kk) {
        const int k0 = kk * 32 + kb;
        half8v a = *(const half8v*)&xs[arow][k0];
        #pragma unroll
        for (int j = 0; j < 8; ++j) {
            half8v b = *(const half8v*)&ws[j * 16 + kcol][k0];
            acc[j] = __builtin_amdgcn_mfma_f32_16x16x32_f16(a, b, acc[j], 0, 0, 0);
        }
    }

    const int rbase = n0 + r0 + (lane >> 4) * 4;
    #pragma unroll
    for (int j = 0; j < 8; ++j) {
        #pragma unroll
        for (int r = 0; r < 4; ++r) {
            int row = rbase + r;
            if (row < n) Hb[(size_t)row * 128 + j * 16 + kcol] = f2h(acc[j][r]);
        }
    }

    float av[8], bv[8];
    #pragma unroll
    for (int j = 0; j < 8; ++j) {
        av[j] = a_src[j * 16 + kcol];
        bv[j] = a_dst[j * 16 + kcol];
    }

    if (H == 4) {
        float ps[4][4], pd[4][4];
        #pragma unroll
        for (int r = 0; r < 4; ++r)
            #pragma unroll
            for (int h = 0; h < 4; ++h) {
                ps[r][h] = acc[2*h][r] * av[2*h] + acc[2*h+1][r] * av[2*h+1];
                pd[r][h] = acc[2*h][r] * bv[2*h] + acc[2*h+1][r] * bv[2*h+1];
            }
        #pragma unroll
        for (int o = 8; o >= 1; o >>= 1)
            #pragma unroll
            for (int r = 0; r < 4; ++r)
                #pragma unroll
                for (int h = 0; h < 4; ++h) {
                    ps[r][h] += __shfl_xor(ps[r][h], o);
                    pd[r][h] += __shfl_xor(pd[r][h], o);
                }
        float wvs = 0.f, wvd = 0.f;
        #pragma unroll
        for (int r = 0; r < 4; ++r)
            #pragma unroll
            for (int h = 0; h < 4; ++h)
                if (kcol == r * 4 + h) { wvs = ps[r][h]; wvd = pd[r][h]; }
        int node = rbase + (kcol >> 2);
        if (node < n) {
            AS[node * 4 + (kcol & 3)] = wvs;
            AD[node * 4 + (kcol & 3)] = wvd;
        }
    } else {
        float ps[4], pd[4];
        #pragma unroll
        for (int r = 0; r < 4; ++r) {
            float s_ = 0.f, d_ = 0.f;
            #pragma unroll
            for (int j = 0; j < 8; ++j) {
                s_ += acc[j][r] * av[j];
                d_ += acc[j][r] * bv[j];
            }
            ps[r] = s_; pd[r] = d_;
        }
        #pragma unroll
        for (int o = 8; o >= 1; o >>= 1)
            #pragma unroll
            for (int r = 0; r < 4; ++r) {
                ps[r] += __shfl_xor(ps[r], o);
                pd[r] += __shfl_xor(pd[r], o);
            }
        float val = 0.f;
        #pragma unroll
        for (int r = 0; r < 4; ++r)
            if ((kcol & 3) == r) val = (kcol < 4) ? ps[r] : pd[r];
        int node = rbase + (kcol & 3);
        if (kcol < 8 && node < n) {
            if (kcol < 4) AS[node] = val;
            else          AD[node] = val;
        }
    }
}

// ---------------- bucketed CSR build ----------------------------------------
// r17: TILE 4096 (2x parallelism, halved per-block serial work); dst cached in
// LDS u16 during the histogram pass (one read of ei[E..] instead of two).
__global__ __launch_bounds__(256) void bucket_append(
    const int* __restrict__ ei, int* __restrict__ bcnt,
    u32* __restrict__ bkt, int E, int etot, int nbkt) {
    __shared__ u32 ent[TILE];
    __shared__ u16 darr[TILE];
    __shared__ int hist[BKT_MAX], lstart[BKT_MAX], gbase[BKT_MAX], cur[BKT_MAX];
    __shared__ int sc[BKT_MAX];
    const int t = threadIdx.x;
    const int e0 = blockIdx.x * TILE;
    const int cnt = min(TILE, etot - e0);

    for (int i = t; i < BKT_MAX; i += 256) { hist[i] = 0; }
    __syncthreads();

    for (int i = t; i < cnt; i += 256) {
        int e = e0 + i;
        int d = (e < E) ? ei[E + e] : e - E;
        darr[i] = (u16)d;
        atomicAdd(&hist[d >> BKT_SH], 1);
    }
    __syncthreads();

    sc[t] = hist[t];
    sc[t + 256] = hist[t + 256];
    __syncthreads();
    for (int off = 1; off < BKT_MAX; off <<= 1) {
        int i0 = t, i1 = t + 256;
        int v0 = (i0 >= off) ? sc[i0 - off] : 0;
        int v1 = (i1 >= off) ? sc[i1 - off] : 0;
        __syncthreads();
        sc[i0] += v0;
        sc[i1] += v1;
        __syncthreads();
    }
    for (int i = t; i < BKT_MAX; i += 256) {
        int ls = sc[i] - hist[i];
        lstart[i] = ls;
        cur[i] = ls;
        gbase[i] = (i < nbkt && hist[i] > 0) ? atomicAdd(&bcnt[i * 16], hist[i]) : 0;
    }
    __syncthreads();

    for (int i = t; i < cnt; i += 256) {
        int e = e0 + i;
        int s = (e < E) ? ei[e] : e - E;
        int d = darr[i];
        int p = atomicAdd(&cur[d >> BKT_SH], 1);
        ent[p] = ((u32)d << 16) | (u32)s;
    }
    __syncthreads();

    for (int i = t; i < cnt; i += 256) {
        u32 en = ent[i];
        int b = en >> (16 + BKT_SH);
        int pos = gbase[b] + (i - lstart[b]);
        if (pos < BKT_CAP) bkt[(size_t)b * BKT_CAP + pos] = en;
    }
}

__global__ __launch_bounds__(256) void bucket_csr(
    const u32* __restrict__ bkt, const int* __restrict__ bcnt,
    int* __restrict__ offsets, int* __restrict__ csr_src,
    int n, int nbkt, int etot) {
    __shared__ u32 ent[BKT_CAP];
    __shared__ int hist[128], pr[128], cur[128];
    __shared__ int sc[BKT_MAX];
    const int b = blockIdx.x;
    const int t = threadIdx.x;

    sc[t]       = (t < nbkt)       ? min(bcnt[t * 16], BKT_CAP) : 0;
    sc[t + 256] = (t + 256 < nbkt) ? min(bcnt[(t + 256) * 16], BKT_CAP) : 0;
    __syncthreads();
    for (int off = 1; off < BKT_MAX; off <<= 1) {
        int i0 = t, i1 = t + 256;
        int v0 = (i0 >= off) ? sc[i0 - off] : 0;
        int v1 = (i1 >= off) ? sc[i1 - off] : 0;
        __syncthreads();
        sc[i0] += v0;
        sc[i1] += v1;
        __syncthreads();
    }
    const int cnt = min(bcnt[b * 16], BKT_CAP);
    const int base = sc[b] - cnt;
    if (b == 0 && t == 0) offsets[n] = etot;

    for (int i = t; i < cnt; i += 256) ent[i] = bkt[(size_t)b * BKT_CAP + i];
    if (t < 128) hist[t] = 0;
    __syncthreads();
    for (int i = t; i < cnt; i += 256) atomicAdd(&hist[(ent[i] >> 16) & 127], 1);
    __syncthreads();
    if (t < 128) pr[t] = hist[t];
    __syncthreads();
    #pragma unroll
    for (int off = 1; off < 128; off <<= 1) {
        int u = (t >= off && t < 128) ? pr[t - off] : 0;
        __syncthreads();
        if (t < 128) pr[t] += u;
        __syncthreads();
    }
    if (t < 128) {
        int excl = pr[t] - hist[t];
        int d = b * 128 + t;
        if (d < n) offsets[d] = base + excl;
        cur[t] = excl;
    }
    __syncthreads();
    for (int i = t; i < cnt; i += 256) {
        u32 en = ent[i];
        int dl = (en >> 16) & 127;
        int pos = base + atomicAdd(&cur[dl], 1);
        csr_src[pos] = (int)(en & 0xFFFFu);
    }
}

// ---------------- single-pass fused softmax + aggregation (fp16 h) -----------
// r15 version (proven 45.8us): one wave/node, alpha slots + shfl broadcast +
// next-chunk prefetch, 4-edges-per-wave-load (uint4 = 8 fp16 channels/lane),
// fma_mix MACs. head of lane's channels = c8>>2.
// MODE 0: OUT fp16, elu(agg+bias);  MODE 1: OUT f32, agg+bias.
template <int H, int MODE>
__global__ __launch_bounds__(256) void node_fused(
    const int* __restrict__ offsets, const int* __restrict__ csr_src,
    const float* __restrict__ AS, const float* __restrict__ AD,
    const u16* __restrict__ Hb, const float* __restrict__ bias,
    void* __restrict__ OUT, int n) {
    const int wid = threadIdx.x >> 6, lane = threadIdx.x & 63;
    const int d = blockIdx.x * 4 + wid;
    if (d >= n) return;
    const int off = offsets[d];
    const int deg = offsets[d + 1] - off;

    constexpr int SCH = (H == 4) ? 32 : 64;
    const int slot = (H == 4) ? (lane & 15) : lane;   // alpha slot
    const int g    = (H == 4) ? (lane >> 4) : 0;      // head this alpha covers
    const float adv = AD[d * H + g];

    const int q  = lane >> 4;                         // edge subslot 0..3
    const int c8 = lane & 15;                         // channels 8*c8..8*c8+7
    const int ghead = (H == 4) ? (c8 >> 2) : 0;       // head of my channels

    float acc[8];
    #pragma unroll
    for (int j = 0; j < 8; ++j) acc[j] = 0.f;
    float smp = 0.f;

    int sA = 0, sB = 0;
    float xA = 0.f, xB = 0.f, vA = 0.f, vB = 0.f;
    {
        int kA = slot; bool a = kA < deg;
        sA = a ? csr_src[off + kA] : 0;
        xA = a ? AS[sA * H + g] : 0.f;
        vA = a ? 1.f : 0.f;
        if (H == 4) {
            int kB = 16 + slot; bool b_ = kB < deg;
            sB = b_ ? csr_src[off + kB] : 0;
            xB = b_ ? AS[sB * H + g] : 0.f;
            vB = b_ ? 1.f : 0.f;
        }
    }

    for (int k0 = 0; k0 < deg; k0 += SCH) {
        float eA = xA + adv; eA = eA > 0.f ? eA : 0.2f * eA;
        float aA = vA * __expf(eA);
        float aB = 0.f;
        if (H == 4) {
            float eB = xB + adv; eB = eB > 0.f ? eB : 0.2f * eB;
            aB = vB * __expf(eB);
        }
        smp += aA + aB;
        const int scA = sA, scB = sB;

        {
            int kA = k0 + SCH + slot; bool a = kA < deg;
            sA = a ? csr_src[off + kA] : 0;
            xA = a ? AS[sA * H + g] : 0.f;
            vA = a ? 1.f : 0.f;
            if (H == 4) {
                int kB = k0 + SCH + 16 + slot; bool b_ = kB < deg;
                sB = b_ ? csr_src[off + kB] : 0;
                xB = b_ ? AS[sB * H + g] : 0.f;
                vB = b_ ? 1.f : 0.f;
            }
        }

        const int rem = min(SCH, deg - k0);
        const int ngr = (rem + 3) >> 2;               // 4-edge groups
        #pragma unroll
        for (int p = 0; p < SCH / 4; ++p) {
            if (p >= ngr) break;                      // wave-uniform
            const int eslot = p * 4 + q;
            float al; int sj;
            if (H == 4) {
                if (p < 4) {
                    al = __shfl(aA, ghead * 16 + eslot);
                    sj = __shfl(scA, ghead * 16 + eslot);
                } else {
                    al = __shfl(aB, ghead * 16 + eslot - 16);
                    sj = __shfl(scB, ghead * 16 + eslot - 16);
                }
            } else {
                al = __shfl(aA, eslot);
                sj = __shfl(scA, eslot);
            }
            uint4 u = *(const uint4*)&Hb[(size_t)sj * 128 + c8 * 8];
            __half2 p0 = *(__half2*)&u.x;
            __half2 p1 = *(__half2*)&u.y;
            __half2 p2 = *(__half2*)&u.z;
            __half2 p3 = *(__half2*)&u.w;
            acc[0] += __low2float(p0) * al; acc[1] += __high2float(p0) * al;
            acc[2] += __low2float(p1) * al; acc[3] += __high2float(p1) * al;
            acc[4] += __low2float(p2) * al; acc[5] += __high2float(p2) * al;
            acc[6] += __low2float(p3) * al; acc[7] += __high2float(p3) * al;
        }
    }

    #pragma unroll
    for (int o = (H == 4 ? 8 : 32); o >= 1; o >>= 1)
        smp += __shfl_xor(smp, o);
    const float den = (H == 4) ? __shfl(smp, ghead * 16) : smp;
    const float dinv = 1.f / den;

    #pragma unroll
    for (int j = 0; j < 8; ++j) {
        acc[j] += __shfl_xor(acc[j], 16);
        acc[j] += __shfl_xor(acc[j], 32);
    }

    if (lane < 16) {
        const float4 bv0 = *(const float4*)&bias[c8 * 8];
        const float4 bv1 = *(const float4*)&bias[c8 * 8 + 4];
        float o_[8];
        o_[0] = acc[0] * dinv + bv0.x; o_[1] = acc[1] * dinv + bv0.y;
        o_[2] = acc[2] * dinv + bv0.z; o_[3] = acc[3] * dinv + bv0.w;
        o_[4] = acc[4] * dinv + bv1.x; o_[5] = acc[5] * dinv + bv1.y;
        o_[6] = acc[6] * dinv + bv1.z; o_[7] = acc[7] * dinv + bv1.w;
        if (MODE == 0) {
            #pragma unroll
            for (int j = 0; j < 8; ++j) o_[j] = o_[j] > 0.f ? o_[j] : expm1f(o_[j]);
            uint4 pk;
            pk.x = (u32)f2h(o_[0]) | ((u32)f2h(o_[1]) << 16);
            pk.y = (u32)f2h(o_[2]) | ((u32)f2h(o_[3]) << 16);
            pk.z = (u32)f2h(o_[4]) | ((u32)f2h(o_[5]) << 16);
            pk.w = (u32)f2h(o_[6]) | ((u32)f2h(o_[7]) << 16);
            *(uint4*)&((u16*)OUT)[(size_t)d * 128 + c8 * 8] = pk;
        } else {
            float* O = (float*)OUT;
            *(float4*)&O[(size_t)d * 128 + c8 * 8]     = make_float4(o_[0], o_[1], o_[2], o_[3]);
            *(float4*)&O[(size_t)d * 128 + c8 * 8 + 4] = make_float4(o_[4], o_[5], o_[6], o_[7]);
        }
    }
}

// ---------------- launch -----------------------------------------------------
extern "C" void kernel_launch(void* const* d_in, const int* in_sizes, int n_in,
                              void* d_out, int out_size, void* d_ws, size_t ws_size,
                              hipStream_t stream) {
    const float* x   = (const float*)d_in[0];
    const int*   ei  = (const int*)d_in[1];
    const float* W1  = (const float*)d_in[2];
    const float* as1 = (const float*)d_in[3];
    const float* ad1 = (const float*)d_in[4];
    const float* b1  = (const float*)d_in[5];
    const float* W2  = (const float*)d_in[6];
    const float* as2 = (const float*)d_in[7];
    const float* ad2 = (const float*)d_in[8];
    const float* b2  = (const float*)d_in[9];
    float* out = (float*)d_out;

    const int n = in_sizes[0] / 128;
    const int E = in_sizes[1] / 2;
    const int etot = E + n;
    const int nbkt = (n + 127) >> BKT_SH;

    char* p = (char*)d_ws;
    u16* Hb1 = (u16*)p; p += (size_t)n * 128 * 2;
    u16* Xb2 = (u16*)p; p += (size_t)n * 128 * 2;
    u16* Hb2 = (u16*)p; p += (size_t)n * 128 * 2;
    float* AS = (float*)p; p += (size_t)n * 4 * 4;
    float* AD = (float*)p; p += (size_t)n * 4 * 4;
    u16* WT1 = (u16*)p; p += 32768;
    u16* WT2 = (u16*)p; p += 32768;
    u32* bkt     = (u32*)p; p += (size_t)BKT_MAX * BKT_CAP * 4;   // 8 MB
    int* bcnt    = (int*)p; p += (size_t)BKT_MAX * 16 * 4;        // line-padded
    int* csr_src = (int*)p; p += (size_t)etot * 4;
    int* offsets = (int*)p; p += (size_t)(n + 1) * 4;

    const int ggrid = (n + 63) / 64;
    const int ngrid = (n + 3) / 4;
    const int agrid = (etot + TILE - 1) / TILE;

    prep_w<<<128, 256, 0, stream>>>(W1, W2, WT1, WT2, bcnt);   // also zeros bcnt
    bucket_append<<<agrid, 256, 0, stream>>>(ei, bcnt, bkt, E, etot, nbkt);
    bucket_csr<<<nbkt, 256, 0, stream>>>(bkt, bcnt, offsets, csr_src, n, nbkt, etot);

    // ---- layer 1 (H=4, concat, ELU fused) ----
    gemm_mfma<0, 4><<<ggrid, 256, 0, stream>>>(x, WT1, as1, ad1, Hb1, AS, AD, n);
    node_fused<4, 0><<<ngrid, 256, 0, stream>>>(offsets, csr_src, AS, AD, Hb1, b1, Xb2, n);

    // ---- layer 2 (H=1, mean over 1 head = identity) ----
    gemm_mfma<1, 1><<<ggrid, 256, 0, stream>>>(Xb2, WT2, as2, ad2, Hb2, AS, AD, n);
    node_fused<1, 1><<<ngrid, 256, 0, stream>>>(offsets, csr_src, AS, AD, Hb2, b2, out, n);
}

// Round 18
// 144.900 us; speedup vs baseline: 1.3069x; 1.0107x over previous
//
#include <hip/hip_runtime.h>
#include <hip/hip_fp16.h>
#include <math.h>

typedef unsigned short u16;
typedef unsigned int u32;
typedef __attribute__((ext_vector_type(8))) _Float16 half8v;
typedef __attribute__((ext_vector_type(4))) float float4v;

#define BKT_SH 7                    // 128 nodes per bucket
#define BKT_CAP 4096                // >> mean occupancy 2176 (uniform dst)
#define BKT_MAX 512                 // max buckets (n <= 65536; src fits 16 bits)
#define TILE 4096                   // edges per bucket_append block

__device__ __forceinline__ u16 f2h(float f) {
    __half h = __float2half(f);
    return __half_as_ushort(h);
}

// ---------------- weight prep: W f32 -> WT [col][k] fp16 ; zeros bcnt --------
__global__ void prep_w(const float* __restrict__ W1, const float* __restrict__ W2,
                       u16* __restrict__ WT1, u16* __restrict__ WT2,
                       int* __restrict__ bcnt) {
    int t = blockIdx.x * 256 + threadIdx.x;   // 32768 total
    if (t < BKT_MAX * 16) bcnt[t] = 0;        // fused memset (8192 ints)
    int which = t >> 14, idx = t & 16383;
    int k = idx >> 7, c = idx & 127;
    const float* W = which ? W2 : W1;
    u16* WT = which ? WT2 : WT1;
    WT[c * 128 + k] = f2h(W[k * 128 + c]);
}

// ---------------- MFMA GEMM (fp16) + fused alpha_src/alpha_dst ---------------
// r18: 128 rows per block (two 64-row tiles share one ws staging) -- halves
// block count and WT re-read traffic vs 64-row blocks.
template <int IN16, int H>
__global__ __launch_bounds__(256) void gemm_mfma(const void* __restrict__ Xv,
                                                 const u16* __restrict__ WT,
                                                 const float* __restrict__ a_src,
                                                 const float* __restrict__ a_dst,
                                                 u16* __restrict__ Hb,
                                                 float* __restrict__ AS,
                                                 float* __restrict__ AD, int n) {
    __shared__ __align__(16) u16 xs[128][136];
    __shared__ __align__(16) u16 ws[128][136];
    const int t = threadIdx.x;
    const int n0 = blockIdx.x * 128;

    {
        const uint4* src = (const uint4*)WT;
        #pragma unroll
        for (int i = 0; i < 8; ++i) {
            int idx = t + i * 256;
            int row = idx >> 4, oct = idx & 15;
            uint4 v = src[idx];
            *(uint4*)&ws[row][oct * 8] = v;
        }
    }
    if (IN16) {
        const u16* X = (const u16*)Xv;
        #pragma unroll
        for (int i = 0; i < 8; ++i) {
            int idx = t + i * 256;              // 2048 x 16B
            int row = idx >> 4, oct = idx & 15;
            uint4 v = make_uint4(0, 0, 0, 0);
            if (n0 + row < n) v = *(const uint4*)&X[(size_t)(n0 + row) * 128 + oct * 8];
            *(uint4*)&xs[row][oct * 8] = v;
        }
    } else {
        const float* X = (const float*)Xv;
        #pragma unroll
        for (int i = 0; i < 16; ++i) {
            int idx = t + i * 256;              // 4096 x float4
            int row = idx >> 5, quad = idx & 31;
            float4 v = make_float4(0.f, 0.f, 0.f, 0.f);
            if (n0 + row < n) v = *(const float4*)&X[(size_t)(n0 + row) * 128 + quad * 4];
            u32 lo = (u32)f2h(v.x) | ((u32)f2h(v.y) << 16);
            u32 hi = (u32)f2h(v.z) | ((u32)f2h(v.w) << 16);
            *(uint2*)&xs[row][quad * 4] = make_uint2(lo, hi);
        }
    }
    __syncthreads();

    const int wave = t >> 6, lane = t & 63;
    const int kcol = lane & 15;
    const int kb = (lane >> 4) * 8;

    #pragma unroll
    for (int tile = 0; tile < 2; ++tile) {
        const int r0 = tile * 64 + wave * 16;
        const int arow = r0 + kcol;

        float4v acc[8];
        #pragma unroll
        for (int j = 0; j < 8; ++j) acc[j] = (float4v){0.f, 0.f, 0.f, 0.f};

        #pragma unroll
        for (int kk = 0; kk < 4; ++kk) {
            const int k0 = kk * 32 + kb;
            half8v a = *(const half8v*)&xs[arow][k0];
            #pragma unroll
            for (int j = 0; j < 8; ++j) {
                half8v b = *(const half8v*)&ws[j * 16 + kcol][k0];
                acc[j] = __builtin_amdgcn_mfma_f32_16x16x32_f16(a, b, acc[j], 0, 0, 0);
            }
        }

        const int rbase = n0 + r0 + (lane >> 4) * 4;
        #pragma unroll
        for (int j = 0; j < 8; ++j) {
            #pragma unroll
            for (int r = 0; r < 4; ++r) {
                int row = rbase + r;
                if (row < n) Hb[(size_t)row * 128 + j * 16 + kcol] = f2h(acc[j][r]);
            }
        }

        float av[8], bv[8];
        #pragma unroll
        for (int j = 0; j < 8; ++j) {
            av[j] = a_src[j * 16 + kcol];
            bv[j] = a_dst[j * 16 + kcol];
        }

        if (H == 4) {
            float ps[4][4], pd[4][4];
            #pragma unroll
            for (int r = 0; r < 4; ++r)
                #pragma unroll
                for (int h = 0; h < 4; ++h) {
                    ps[r][h] = acc[2*h][r] * av[2*h] + acc[2*h+1][r] * av[2*h+1];
                    pd[r][h] = acc[2*h][r] * bv[2*h] + acc[2*h+1][r] * bv[2*h+1];
                }
            #pragma unroll
            for (int o = 8; o >= 1; o >>= 1)
                #pragma unroll
                for (int r = 0; r < 4; ++r)
                    #pragma unroll
                    for (int h = 0; h < 4; ++h) {
                        ps[r][h] += __shfl_xor(ps[r][h], o);
                        pd[r][h] += __shfl_xor(pd[r][h], o);
                    }
            float wvs = 0.f, wvd = 0.f;
            #pragma unroll
            for (int r = 0; r < 4; ++r)
                #pragma unroll
                for (int h = 0; h < 4; ++h)
                    if (kcol == r * 4 + h) { wvs = ps[r][h]; wvd = pd[r][h]; }
            int node = rbase + (kcol >> 2);
            if (node < n) {
                AS[node * 4 + (kcol & 3)] = wvs;
                AD[node * 4 + (kcol & 3)] = wvd;
            }
        } else {
            float ps[4], pd[4];
            #pragma unroll
            for (int r = 0; r < 4; ++r) {
                float s_ = 0.f, d_ = 0.f;
                #pragma unroll
                for (int j = 0; j < 8; ++j) {
                    s_ += acc[j][r] * av[j];
                    d_ += acc[j][r] * bv[j];
                }
                ps[r] = s_; pd[r] = d_;
            }
            #pragma unroll
            for (int o = 8; o >= 1; o >>= 1)
                #pragma unroll
                for (int r = 0; r < 4; ++r) {
                    ps[r] += __shfl_xor(ps[r], o);
                    pd[r] += __shfl_xor(pd[r], o);
                }
            float val = 0.f;
            #pragma unroll
            for (int r = 0; r < 4; ++r)
                if ((kcol & 3) == r) val = (kcol < 4) ? ps[r] : pd[r];
            int node = rbase + (kcol & 3);
            if (kcol < 8 && node < n) {
                if (kcol < 4) AS[node] = val;
                else          AD[node] = val;
            }
        }
    }
}

// ---------------- bucketed CSR build ----------------------------------------
__global__ __launch_bounds__(256) void bucket_append(
    const int* __restrict__ ei, int* __restrict__ bcnt,
    u32* __restrict__ bkt, int E, int etot, int nbkt) {
    __shared__ u32 ent[TILE];
    __shared__ u16 darr[TILE];
    __shared__ int hist[BKT_MAX], lstart[BKT_MAX], gbase[BKT_MAX], cur[BKT_MAX];
    __shared__ int sc[BKT_MAX];
    const int t = threadIdx.x;
    const int e0 = blockIdx.x * TILE;
    const int cnt = min(TILE, etot - e0);

    for (int i = t; i < BKT_MAX; i += 256) { hist[i] = 0; }
    __syncthreads();

    for (int i = t; i < cnt; i += 256) {
        int e = e0 + i;
        int d = (e < E) ? ei[E + e] : e - E;
        darr[i] = (u16)d;
        atomicAdd(&hist[d >> BKT_SH], 1);
    }
    __syncthreads();

    sc[t] = hist[t];
    sc[t + 256] = hist[t + 256];
    __syncthreads();
    for (int off = 1; off < BKT_MAX; off <<= 1) {
        int i0 = t, i1 = t + 256;
        int v0 = (i0 >= off) ? sc[i0 - off] : 0;
        int v1 = (i1 >= off) ? sc[i1 - off] : 0;
        __syncthreads();
        sc[i0] += v0;
        sc[i1] += v1;
        __syncthreads();
    }
    for (int i = t; i < BKT_MAX; i += 256) {
        int ls = sc[i] - hist[i];
        lstart[i] = ls;
        cur[i] = ls;
        gbase[i] = (i < nbkt && hist[i] > 0) ? atomicAdd(&bcnt[i * 16], hist[i]) : 0;
    }
    __syncthreads();

    for (int i = t; i < cnt; i += 256) {
        int e = e0 + i;
        int s = (e < E) ? ei[e] : e - E;
        int d = darr[i];
        int p = atomicAdd(&cur[d >> BKT_SH], 1);
        ent[p] = ((u32)d << 16) | (u32)s;
    }
    __syncthreads();

    for (int i = t; i < cnt; i += 256) {
        u32 en = ent[i];
        int b = en >> (16 + BKT_SH);
        int pos = gbase[b] + (i - lstart[b]);
        if (pos < BKT_CAP) bkt[(size_t)b * BKT_CAP + pos] = en;
    }
}

__global__ __launch_bounds__(256) void bucket_csr(
    const u32* __restrict__ bkt, const int* __restrict__ bcnt,
    int* __restrict__ offsets, int* __restrict__ csr_src,
    int n, int nbkt, int etot) {
    __shared__ u32 ent[BKT_CAP];
    __shared__ int hist[128], pr[128], cur[128];
    __shared__ int sc[BKT_MAX];
    const int b = blockIdx.x;
    const int t = threadIdx.x;

    sc[t]       = (t < nbkt)       ? min(bcnt[t * 16], BKT_CAP) : 0;
    sc[t + 256] = (t + 256 < nbkt) ? min(bcnt[(t + 256) * 16], BKT_CAP) : 0;
    __syncthreads();
    for (int off = 1; off < BKT_MAX; off <<= 1) {
        int i0 = t, i1 = t + 256;
        int v0 = (i0 >= off) ? sc[i0 - off] : 0;
        int v1 = (i1 >= off) ? sc[i1 - off] : 0;
        __syncthreads();
        sc[i0] += v0;
        sc[i1] += v1;
        __syncthreads();
    }
    const int cnt = min(bcnt[b * 16], BKT_CAP);
    const int base = sc[b] - cnt;
    if (b == 0 && t == 0) offsets[n] = etot;

    for (int i = t; i < cnt; i += 256) ent[i] = bkt[(size_t)b * BKT_CAP + i];
    if (t < 128) hist[t] = 0;
    __syncthreads();
    for (int i = t; i < cnt; i += 256) atomicAdd(&hist[(ent[i] >> 16) & 127], 1);
    __syncthreads();
    if (t < 128) pr[t] = hist[t];
    __syncthreads();
    #pragma unroll
    for (int off = 1; off < 128; off <<= 1) {
        int u = (t >= off && t < 128) ? pr[t - off] : 0;
        __syncthreads();
        if (t < 128) pr[t] += u;
        __syncthreads();
    }
    if (t < 128) {
        int excl = pr[t] - hist[t];
        int d = b * 128 + t;
        if (d < n) offsets[d] = base + excl;
        cur[t] = excl;
    }
    __syncthreads();
    for (int i = t; i < cnt; i += 256) {
        u32 en = ent[i];
        int dl = (en >> 16) & 127;
        int pos = base + atomicAdd(&cur[dl], 1);
        csr_src[pos] = (int)(en & 0xFFFFu);
    }
}

// ---------------- single-pass fused softmax + aggregation (fp16 h) -----------
// r15/r17 version (proven 45.8us floor): one wave/node, alpha slots + shfl
// broadcast + next-chunk prefetch, 4-edges-per-wave-load (uint4/lane).
// MODE 0: OUT fp16, elu(agg+bias);  MODE 1: OUT f32, agg+bias.
template <int H, int MODE>
__global__ __launch_bounds__(256) void node_fused(
    const int* __restrict__ offsets, const int* __restrict__ csr_src,
    const float* __restrict__ AS, const float* __restrict__ AD,
    const u16* __restrict__ Hb, const float* __restrict__ bias,
    void* __restrict__ OUT, int n) {
    const int wid = threadIdx.x >> 6, lane = threadIdx.x & 63;
    const int d = blockIdx.x * 4 + wid;
    if (d >= n) return;
    const int off = offsets[d];
    const int deg = offsets[d + 1] - off;

    constexpr int SCH = (H == 4) ? 32 : 64;
    const int slot = (H == 4) ? (lane & 15) : lane;
    const int g    = (H == 4) ? (lane >> 4) : 0;
    const float adv = AD[d * H + g];

    const int q  = lane >> 4;
    const int c8 = lane & 15;
    const int ghead = (H == 4) ? (c8 >> 2) : 0;

    float acc[8];
    #pragma unroll
    for (int j = 0; j < 8; ++j) acc[j] = 0.f;
    float smp = 0.f;

    int sA = 0, sB = 0;
    float xA = 0.f, xB = 0.f, vA = 0.f, vB = 0.f;
    {
        int kA = slot; bool a = kA < deg;
        sA = a ? csr_src[off + kA] : 0;
        xA = a ? AS[sA * H + g] : 0.f;
        vA = a ? 1.f : 0.f;
        if (H == 4) {
            int kB = 16 + slot; bool b_ = kB < deg;
            sB = b_ ? csr_src[off + kB] : 0;
            xB = b_ ? AS[sB * H + g] : 0.f;
            vB = b_ ? 1.f : 0.f;
        }
    }

    for (int k0 = 0; k0 < deg; k0 += SCH) {
        float eA = xA + adv; eA = eA > 0.f ? eA : 0.2f * eA;
        float aA = vA * __expf(eA);
        float aB = 0.f;
        if (H == 4) {
            float eB = xB + adv; eB = eB > 0.f ? eB : 0.2f * eB;
            aB = vB * __expf(eB);
        }
        smp += aA + aB;
        const int scA = sA, scB = sB;

        {
            int kA = k0 + SCH + slot; bool a = kA < deg;
            sA = a ? csr_src[off + kA] : 0;
            xA = a ? AS[sA * H + g] : 0.f;
            vA = a ? 1.f : 0.f;
            if (H == 4) {
                int kB = k0 + SCH + 16 + slot; bool b_ = kB < deg;
                sB = b_ ? csr_src[off + kB] : 0;
                xB = b_ ? AS[sB * H + g] : 0.f;
                vB = b_ ? 1.f : 0.f;
            }
        }

        const int rem = min(SCH, deg - k0);
        const int ngr = (rem + 3) >> 2;
        #pragma unroll
        for (int p = 0; p < SCH / 4; ++p) {
            if (p >= ngr) break;
            const int eslot = p * 4 + q;
            float al; int sj;
            if (H == 4) {
                if (p < 4) {
                    al = __shfl(aA, ghead * 16 + eslot);
                    sj = __shfl(scA, ghead * 16 + eslot);
                } else {
                    al = __shfl(aB, ghead * 16 + eslot - 16);
                    sj = __shfl(scB, ghead * 16 + eslot - 16);
                }
            } else {
                al = __shfl(aA, eslot);
                sj = __shfl(scA, eslot);
            }
            uint4 u = *(const uint4*)&Hb[(size_t)sj * 128 + c8 * 8];
            __half2 p0 = *(__half2*)&u.x;
            __half2 p1 = *(__half2*)&u.y;
            __half2 p2 = *(__half2*)&u.z;
            __half2 p3 = *(__half2*)&u.w;
            acc[0] += __low2float(p0) * al; acc[1] += __high2float(p0) * al;
            acc[2] += __low2float(p1) * al; acc[3] += __high2float(p1) * al;
            acc[4] += __low2float(p2) * al; acc[5] += __high2float(p2) * al;
            acc[6] += __low2float(p3) * al; acc[7] += __high2float(p3) * al;
        }
    }

    #pragma unroll
    for (int o = (H == 4 ? 8 : 32); o >= 1; o >>= 1)
        smp += __shfl_xor(smp, o);
    const float den = (H == 4) ? __shfl(smp, ghead * 16) : smp;
    const float dinv = 1.f / den;

    #pragma unroll
    for (int j = 0; j < 8; ++j) {
        acc[j] += __shfl_xor(acc[j], 16);
        acc[j] += __shfl_xor(acc[j], 32);
    }

    if (lane < 16) {
        const float4 bv0 = *(const float4*)&bias[c8 * 8];
        const float4 bv1 = *(const float4*)&bias[c8 * 8 + 4];
        float o_[8];
        o_[0] = acc[0] * dinv + bv0.x; o_[1] = acc[1] * dinv + bv0.y;
        o_[2] = acc[2] * dinv + bv0.z; o_[3] = acc[3] * dinv + bv0.w;
        o_[4] = acc[4] * dinv + bv1.x; o_[5] = acc[5] * dinv + bv1.y;
        o_[6] = acc[6] * dinv + bv1.z; o_[7] = acc[7] * dinv + bv1.w;
        if (MODE == 0) {
            #pragma unroll
            for (int j = 0; j < 8; ++j) o_[j] = o_[j] > 0.f ? o_[j] : expm1f(o_[j]);
            uint4 pk;
            pk.x = (u32)f2h(o_[0]) | ((u32)f2h(o_[1]) << 16);
            pk.y = (u32)f2h(o_[2]) | ((u32)f2h(o_[3]) << 16);
            pk.z = (u32)f2h(o_[4]) | ((u32)f2h(o_[5]) << 16);
            pk.w = (u32)f2h(o_[6]) | ((u32)f2h(o_[7]) << 16);
            *(uint4*)&((u16*)OUT)[(size_t)d * 128 + c8 * 8] = pk;
        } else {
            float* O = (float*)OUT;
            *(float4*)&O[(size_t)d * 128 + c8 * 8]     = make_float4(o_[0], o_[1], o_[2], o_[3]);
            *(float4*)&O[(size_t)d * 128 + c8 * 8 + 4] = make_float4(o_[4], o_[5], o_[6], o_[7]);
        }
    }
}

// ---------------- launch -----------------------------------------------------
extern "C" void kernel_launch(void* const* d_in, const int* in_sizes, int n_in,
                              void* d_out, int out_size, void* d_ws, size_t ws_size,
                              hipStream_t stream) {
    const float* x   = (const float*)d_in[0];
    const int*   ei  = (const int*)d_in[1];
    const float* W1  = (const float*)d_in[2];
    const float* as1 = (const float*)d_in[3];
    const float* ad1 = (const float*)d_in[4];
    const float* b1  = (const float*)d_in[5];
    const float* W2  = (const float*)d_in[6];
    const float* as2 = (const float*)d_in[7];
    const float* ad2 = (const float*)d_in[8];
    const float* b2  = (const float*)d_in[9];
    float* out = (float*)d_out;

    const int n = in_sizes[0] / 128;
    const int E = in_sizes[1] / 2;
    const int etot = E + n;
    const int nbkt = (n + 127) >> BKT_SH;

    char* p = (char*)d_ws;
    u16* Hb1 = (u16*)p; p += (size_t)n * 128 * 2;
    u16* Xb2 = (u16*)p; p += (size_t)n * 128 * 2;
    u16* Hb2 = (u16*)p; p += (size_t)n * 128 * 2;
    float* AS = (float*)p; p += (size_t)n * 4 * 4;
    float* AD = (float*)p; p += (size_t)n * 4 * 4;
    u16* WT1 = (u16*)p; p += 32768;
    u16* WT2 = (u16*)p; p += 32768;
    u32* bkt     = (u32*)p; p += (size_t)BKT_MAX * BKT_CAP * 4;   // 8 MB
    int* bcnt    = (int*)p; p += (size_t)BKT_MAX * 16 * 4;        // line-padded
    int* csr_src = (int*)p; p += (size_t)etot * 4;
    int* offsets = (int*)p; p += (size_t)(n + 1) * 4;

    const int ggrid = (n + 127) / 128;   // 128 rows/block (r18)
    const int ngrid = (n + 3) / 4;
    const int agrid = (etot + TILE - 1) / TILE;

    prep_w<<<128, 256, 0, stream>>>(W1, W2, WT1, WT2, bcnt);   // also zeros bcnt
    bucket_append<<<agrid, 256, 0, stream>>>(ei, bcnt, bkt, E, etot, nbkt);
    bucket_csr<<<nbkt, 256, 0, stream>>>(bkt, bcnt, offsets, csr_src, n, nbkt, etot);

    // ---- layer 1 (H=4, concat, ELU fused) ----
    gemm_mfma<0, 4><<<ggrid, 256, 0, stream>>>(x, WT1, as1, ad1, Hb1, AS, AD, n);
    node_fused<4, 0><<<ngrid, 256, 0, stream>>>(offsets, csr_src, AS, AD, Hb1, b1, Xb2, n);

    // ---- layer 2 (H=1, mean over 1 head = identity) ----
    gemm_mfma<1, 1><<<ggrid, 256, 0, stream>>>(Xb2, WT2, as2, ad2, Hb2, AS, AD, n);
    node_fused<1, 1><<<ngrid, 256, 0, stream>>>(offsets, csr_src, AS, AD, Hb2, b2, out, n);
}